// Round 4
// baseline (415.555 us; speedup 1.0000x reference)
//
#include <hip/hip_runtime.h>
#include <hip/hip_bf16.h>
#include <math.h>

#define BB 2
#define SS 2048
#define HH 16
#define DH 64
#define DQK 128
#define DD (HH*DH)
// Q folded scale = (1/sqrt(128)) * log2(e)  -> scores arrive in log2 domain
#define QS2   0.12751758f
// 8 * log2(e): fixed-max bias in log2 domain (cancels exactly in softmax).
// NOTE: fixed bias (not running max) => split-K partials combine ADDITIVELY.
#define EBIAS 11.5415605f

typedef _Float16 half8_t __attribute__((ext_vector_type(8)));
typedef _Float16 half4_t __attribute__((ext_vector_type(4)));
typedef __fp16  fp16x2_t __attribute__((ext_vector_type(2)));   // cvt_pkrtz result type
typedef float f32x4_t __attribute__((ext_vector_type(4)));
typedef float f32x4v __attribute__((ext_vector_type(4)));

__device__ __forceinline__ void fsincos(float th, float* sn, float* cs) {
  float rev = th * 0.15915494309189535f;
  rev -= floorf(rev);
  float ang = rev * 6.283185307179586f;
  *sn = __sinf(ang);
  *cs = __cosf(ang);
}

// async global->LDS DMA, 16B/lane, LDS dest = uniform base + lane*16
__device__ __forceinline__ void dma16(const void* g, void* l) {
  __builtin_amdgcn_global_load_lds(
      (const __attribute__((address_space(1))) unsigned int*)g,
      (__attribute__((address_space(3))) unsigned int*)l, 16, 0, 0);
}

// Block per (bh, s-tile of 64). Emits:
//   Q  row-major [bh][s][128], scale QS2 folded (log2-domain scores)
//   K  swizzled  [bh][ktile64][d8 0..15][key 0..63] 16B units
//   V  swizzled  [bh][ktile64][k8 0..7][dv 0..63]  16B units
__global__ __launch_bounds__(256) void gen_qkv(
    const float* __restrict__ x,
    const float* __restrict__ wq, const float* __restrict__ bq,
    const float* __restrict__ phq,
    const float* __restrict__ wk, const float* __restrict__ bk,
    const float* __restrict__ phk,
    const float* __restrict__ wv, const float* __restrict__ bv,
    _Float16* __restrict__ Qd, _Float16* __restrict__ Kd, _Float16* __restrict__ Vtd)
{
  int stile = blockIdx.x & 31;
  int bh    = blockIdx.x >> 5;
  int b = bh >> 4, h = bh & 15;
  int t = threadIdx.x;
  int sl = t >> 2;                 // 0..63 (key/row within tile)
  int dq = (t & 3) << 4;           // 0,16,32,48
  int s  = stile * 64 + sl;

  __shared__ _Float16 Vl[64 * 65]; // transpose buffer, odd pitch

  const float* xr = x + (((size_t)b * SS + s) * HH + h) * DH + dq;
  float xv[16];
#pragma unroll
  for (int i = 0; i < 4; i++)
    *(f32x4v*)(&xv[i * 4]) = *(const f32x4v*)(xr + i * 4);

  int hd0 = h * DH + dq;
  float iwqv[16], vbq[16], vpq[16];
  float iwkv[16], vbk[16], vpk[16];
  float iwvv[16], vbv[16];
#pragma unroll
  for (int i = 0; i < 4; i++) {
    f32x4v w4, b4, p4;
    w4 = *(const f32x4v*)(wq + hd0 + i * 4);
    b4 = *(const f32x4v*)(bq + hd0 + i * 4);
    p4 = *(const f32x4v*)(phq + hd0 + i * 4);
#pragma unroll
    for (int j = 0; j < 4; j++) {
      iwqv[i*4+j] = __builtin_amdgcn_rcpf(1.f + fabsf(w4[j]));
      vbq[i*4+j] = b4[j]; vpq[i*4+j] = p4[j];
    }
    w4 = *(const f32x4v*)(wk + hd0 + i * 4);
    b4 = *(const f32x4v*)(bk + hd0 + i * 4);
    p4 = *(const f32x4v*)(phk + hd0 + i * 4);
#pragma unroll
    for (int j = 0; j < 4; j++) {
      iwkv[i*4+j] = __builtin_amdgcn_rcpf(1.f + fabsf(w4[j]));
      vbk[i*4+j] = b4[j]; vpk[i*4+j] = p4[j];
    }
    w4 = *(const f32x4v*)(wv + hd0 + i * 4);
    b4 = *(const f32x4v*)(bv + hd0 + i * 4);
#pragma unroll
    for (int j = 0; j < 4; j++) {
      iwvv[i*4+j] = __builtin_amdgcn_rcpf(1.f + fabsf(w4[j]));
      vbv[i*4+j] = b4[j];
    }
  }

  float tv = (float)s;
  _Float16 qc[16], qs[16], kc[16], ks[16];
#pragma unroll
  for (int i = 0; i < 16; i++) {
    int d = dq + i;
    {
      float th = xv[i] * iwqv[i] + vbq[i] + tv * vpq[i];
      float sn, cs; fsincos(th, &sn, &cs);
      qc[i] = (_Float16)(cs * QS2);
      qs[i] = (_Float16)(sn * QS2);
    }
    {
      float th = xv[i] * iwkv[i] + vbk[i] + tv * vpk[i];
      float sn, cs; fsincos(th, &sn, &cs);
      kc[i] = (_Float16)cs;
      ks[i] = (_Float16)sn;
    }
    {
      float th = xv[i] * iwvv[i] + vbv[i];
      float sn, cs; fsincos(th, &sn, &cs);
      Vl[d * 65 + sl] = (_Float16)(cs + sn);
    }
  }
  // Q row-major
  size_t qbase = ((size_t)bh * SS + s) * DQK;
#pragma unroll
  for (int i = 0; i < 2; i++) {
    *(half8_t*)(Qd + qbase + dq + i * 8)      = *(half8_t*)(&qc[i * 8]);
    *(half8_t*)(Qd + qbase + DH + dq + i * 8) = *(half8_t*)(&qs[i * 8]);
  }
  // K swizzled: cos dims d -> d8 = d/8; sin dims -> d8 = 8 + d/8
  {
    size_t ktb = ((size_t)bh * 32 + stile) * 8192;  // f16 base of 16KB tile
    int fo0 = (t & 3) * 2;
    *(half8_t*)(Kd + ktb + ((size_t)(fo0    ) * 64 + sl) * 8) = *(half8_t*)(&kc[0]);
    *(half8_t*)(Kd + ktb + ((size_t)(fo0 + 1) * 64 + sl) * 8) = *(half8_t*)(&kc[8]);
    *(half8_t*)(Kd + ktb + ((size_t)(fo0 + 8) * 64 + sl) * 8) = *(half8_t*)(&ks[0]);
    *(half8_t*)(Kd + ktb + ((size_t)(fo0 + 9) * 64 + sl) * 8) = *(half8_t*)(&ks[8]);
  }
  __syncthreads();
  // V swizzled: unit (k8, dv) = V[dv][keys k8*8..+7]; 2 units/thread, coalesced
#pragma unroll
  for (int i = 0; i < 2; i++) {
    int u = t * 2 + i;
    int dv = u & 63, ku = u >> 6;    // ku 0..7
    _Float16 tmp[8];
#pragma unroll
    for (int jj = 0; jj < 8; jj++) tmp[jj] = Vl[dv * 65 + ku * 8 + jj];
    *(half8_t*)(Vtd + (((size_t)bh * 32 + stile) * 8 + ku) * 512 + dv * 8) =
        *(half8_t*)tmp;
  }
}

// R9: persistent workers + split-K.
// Work items: per bh, qt 0..15 -> one item ([0,nch)); qt 16..31 -> two split
// items [0,h) and [h,nch), h=nch/2. Max item = 16 chunk-units (was 32 -- the
// nch=32 items floored the makespan at 32 units vs 22 avg; measured
// occupancy-of-ceiling 63% matched 22/32). 1536 items / 768 workers.
// 8 per-XCD queues (block bi -> XCD bi%8; queue q holds bh%8==q) keep K/V
// on one XCD's L2; LPT order via kTab; stealing when own queue drains.
// Split combine: fixed-EBIAS softmax => partials (O,l) ADD. First finisher
// stores its per-thread blob (36 f32) + threadfence; second finisher (flag
// atomicAdd) reads counterpart blob, adds in-reg, runs epilogue. No spinning.
__device__ const unsigned char kTab[48] = {
  125,127,123, 60,121,117,119,115, 56,113,109,111,107, 52,105,101,
  103, 99, 48, 97, 93, 95, 91, 44, 89, 85, 87, 83, 40, 81, 77, 79,
   75, 36, 73, 69, 71, 67, 32, 65, 28, 24, 20, 16, 12,  8,  4,  0};

__global__ __launch_bounds__(256) void flash_attn(
    const _Float16* __restrict__ Qd, const _Float16* __restrict__ Kd,
    const _Float16* __restrict__ Vtd,
    const float* __restrict__ wout, const float* __restrict__ bout,
    float* __restrict__ out,
    unsigned* __restrict__ ctr, unsigned* __restrict__ flags,
    float* __restrict__ blobs)
{
  int myq = blockIdx.x & 7;          // dispatch round-robin: XCD = blockIdx%8
  int wave = threadIdx.x >> 6;
  int lane = threadIdx.x & 63;
  int lm = lane & 15, lq = lane >> 4;
  int qh = wave >> 1;
  int kh = wave & 1;

  __shared__ __align__(16) _Float16 KV[2][12288];   // per buf: K 16KB + V 8KB
  __shared__ int sItem;

  for (;;) {
    __syncthreads();                 // protects KV reuse across items
    if (threadIdx.x == 0) {
      int got = -1;
      for (int a = 0; a < 8; a++) {
        int qq = (myq + a) & 7;
        unsigned v = atomicAdd(&ctr[qq], 1u);
        if (v < 192u) { got = (qq << 8) | (int)v; break; }
      }
      sItem = got;
    }
    __syncthreads();
    int it = sItem;
    if (it < 0) break;
    int qq = it >> 8, u = it & 255;
    int bh = qq + 8 * (u & 3);
    int code = kTab[u >> 2];
    int st = code & 1, sp = (code >> 1) & 1, qt = code >> 2;
    int nch = qt + 1, hhalf = nch >> 1;
    int c0 = st ? (sp ? hhalf : 0) : 0;
    int c1 = st ? (sp ? nch : hhalf) : nch;

    int b = bh >> 4, hh = bh & 15;
    int q0 = qt * 64;

    const _Float16* Kg = Kd + (size_t)bh * 32 * 8192;
    const _Float16* Vg = Vtd + (size_t)bh * 32 * 4096;

    {  // preload chunk c0 -> buf c0&1 (flies while Q frags load below)
      const _Float16* gK = Kg + (size_t)c0 * 8192;
      const _Float16* gV = Vg + (size_t)c0 * 4096;
      int nb = c0 & 1;
#pragma unroll
      for (int i = 0; i < 4; i++)
        dma16(gK + (size_t)(wave * 4 + i) * 512 + lane * 8, &KV[nb][(wave * 4 + i) * 512]);
#pragma unroll
      for (int i = 0; i < 2; i++)
        dma16(gV + (size_t)(wave * 2 + i) * 512 + lane * 8, &KV[nb][8192 + (wave * 2 + i) * 512]);
    }

    // Q B-frags resident: B[n=q][k=c*32+lq*8+j]
    const _Float16* Qb = Qd + ((size_t)bh * SS + q0 + qh * 32) * DQK;
    half8_t aq[2][4];
#pragma unroll
    for (int qtl = 0; qtl < 2; qtl++)
#pragma unroll
      for (int c = 0; c < 4; c++)
        aq[qtl][c] = *(const half8_t*)(Qb + (qtl * 16 + lm) * DQK + c * 32 + lq * 8);

    f32x4_t o[4][2];   // [dv-tile][q-tile], elem = O^T[dt*16+lq*4+r][qtl*16+lm]
    float l[2] = {0.f, 0.f};
#pragma unroll
    for (int dt = 0; dt < 4; dt++)
#pragma unroll
      for (int qtl = 0; qtl < 2; qtl++) o[dt][qtl] = (f32x4_t){0.f, 0.f, 0.f, 0.f};

    const f32x4_t cinit = (f32x4_t){-EBIAS, -EBIAS, -EBIAS, -EBIAS};

    for (int kt = c0; kt < c1; ++kt) {
      int bf = kt & 1;
      __syncthreads();   // drains DMA of kt (vmcnt0 before barrier) + compute kt-1
      if (kt + 1 < c1) {
        int nb = (kt + 1) & 1;
        const _Float16* gK = Kg + (size_t)(kt + 1) * 8192;
        const _Float16* gV = Vg + (size_t)(kt + 1) * 4096;
#pragma unroll
        for (int i = 0; i < 4; i++)
          dma16(gK + (size_t)(wave * 4 + i) * 512 + lane * 8, &KV[nb][(wave * 4 + i) * 512]);
#pragma unroll
        for (int i = 0; i < 2; i++)
          dma16(gV + (size_t)(wave * 2 + i) * 512 + lane * 8, &KV[nb][8192 + (wave * 2 + i) * 512]);
      }

      const _Float16* lK = &KV[bf][0];
      const _Float16* lV = &KV[bf][8192];
      int k0 = kt * 64;

      // S^T - EBIAS = K Q^T + (-EBIAS) : C-layout (key = lq*4+r, q = lm)
      f32x4_t cST[2][2];
      cST[0][0] = cST[0][1] = cST[1][0] = cST[1][1] = cinit;
#pragma unroll
      for (int c = 0; c < 4; c++) {
        half8_t k0f = *(const half8_t*)(lK + ((size_t)(c * 4 + lq) * 64 + kh * 32 + lm) * 8);
        half8_t k1f = *(const half8_t*)(lK + ((size_t)(c * 4 + lq) * 64 + kh * 32 + 16 + lm) * 8);
        cST[0][0] = __builtin_amdgcn_mfma_f32_16x16x32_f16(k0f, aq[0][c], cST[0][0], 0, 0, 0);
        cST[0][1] = __builtin_amdgcn_mfma_f32_16x16x32_f16(k0f, aq[1][c], cST[0][1], 0, 0, 0);
        cST[1][0] = __builtin_amdgcn_mfma_f32_16x16x32_f16(k1f, aq[0][c], cST[1][0], 0, 0, 0);
        cST[1][1] = __builtin_amdgcn_mfma_f32_16x16x32_f16(k1f, aq[1][c], cST[1][1], 0, 0, 0);
      }

      // p = 2^(s2) in-register; pack -> B-frags (B[n=q=lm][k=lq*4+i])
      bool maskit = (kt == nch - 1);   // only reachable when c1 == nch
      half4_t pb[2][2];
#pragma unroll
      for (int ktl = 0; ktl < 2; ktl++)
#pragma unroll
        for (int qtl = 0; qtl < 2; qtl++) {
          float pf[4];
#pragma unroll
          for (int r = 0; r < 4; r++) {
            float sv = cST[ktl][qtl][r];
            if (maskit) {
              int key  = k0 + kh * 32 + ktl * 16 + lq * 4 + r;
              int qrow = q0 + qh * 32 + qtl * 16 + lm;
              if (key > qrow) sv = -1e30f;
            }
            pf[r] = __builtin_exp2f(sv);
            l[qtl] += pf[r];
          }
          fp16x2_t h01 = __builtin_amdgcn_cvt_pkrtz(pf[0], pf[1]);
          fp16x2_t h23 = __builtin_amdgcn_cvt_pkrtz(pf[2], pf[3]);
          pb[ktl][qtl] = (half4_t){(_Float16)h01.x, (_Float16)h01.y,
                                   (_Float16)h23.x, (_Float16)h23.y};
        }

      // O^T += V^T P^T : A = V^T frag (m=dv, k=key lq*4+i), 16 MFMA 16x16x16
#pragma unroll
      for (int dt = 0; dt < 4; dt++)
#pragma unroll
        for (int kg = 0; kg < 2; kg++) {
          half4_t vf = *(const half4_t*)(lV +
              ((size_t)(kh * 4 + kg * 2 + (lq >> 1)) * 64 + dt * 16 + lm) * 8 + (lq & 1) * 4);
          o[dt][0] = __builtin_amdgcn_mfma_f32_16x16x16f16(vf, pb[kg][0], o[dt][0], 0, 0, 0);
          o[dt][1] = __builtin_amdgcn_mfma_f32_16x16x16f16(vf, pb[kg][1], o[dt][1], 0, 0, 0);
        }
    }

    // reduce l over lq groups (keys): all lanes end with l for q = qtl*16+lm
#pragma unroll
    for (int qtl = 0; qtl < 2; qtl++) {
      l[qtl] += __shfl_xor(l[qtl], 16);
      l[qtl] += __shfl_xor(l[qtl], 32);
    }

    if (st) {   // split item: store partial; second finisher combines
      int pair = bh * 16 + (qt - 16);          // 0..511
      float* myb = blobs + ((size_t)(pair * 2 + sp) * 256 + threadIdx.x) * 36;
#pragma unroll
      for (int dt = 0; dt < 4; dt++)
#pragma unroll
        for (int qtl = 0; qtl < 2; qtl++)
          *(f32x4_t*)(myb + (dt * 2 + qtl) * 4) = o[dt][qtl];
      myb[32] = l[0]; myb[33] = l[1];
      __threadfence();
      __syncthreads();
      if (threadIdx.x == 0) sItem = (int)atomicAdd(&flags[pair], 1u);
      __syncthreads();
      if (sItem == 0) continue;                // first finisher: done
      __threadfence();
      const float* ob = blobs + ((size_t)(pair * 2 + (sp ^ 1)) * 256 + threadIdx.x) * 36;
#pragma unroll
      for (int dt = 0; dt < 4; dt++)
#pragma unroll
        for (int qtl = 0; qtl < 2; qtl++) {
          f32x4_t p = *(const f32x4_t*)(ob + (dt * 2 + qtl) * 4);
          o[dt][qtl] += p;
        }
      l[0] += ob[32]; l[1] += ob[33];
    }

    // combine kh halves + normalize via LDS overlay (all DMA idle post-loop).
    // Row-major Of[row][pitch 68], 17664 B < 24576 B (stays within KV[0]).
    float* Of = (float*)&KV[0][0];
    float* Lf = Of + 64 * 68;
    __syncthreads();
    if (kh == 1) {
#pragma unroll
      for (int qtl = 0; qtl < 2; qtl++) {
        int row = qh * 32 + qtl * 16 + lm;
#pragma unroll
        for (int dt = 0; dt < 4; dt++)
#pragma unroll
          for (int rr = 0; rr < 4; rr++)
            Of[row * 68 + dt * 16 + lq * 4 + rr] = o[dt][qtl][rr];
        if (lq == 0) Lf[row] = l[qtl];
      }
    }
    __syncthreads();
    if (kh == 0) {
#pragma unroll
      for (int qtl = 0; qtl < 2; qtl++) {
        int row = qh * 32 + qtl * 16 + lm;
        float rl = __builtin_amdgcn_rcpf(l[qtl] + Lf[row]);
#pragma unroll
        for (int dt = 0; dt < 4; dt++)
#pragma unroll
          for (int rr = 0; rr < 4; rr++) {
            int idx = row * 68 + dt * 16 + lq * 4 + rr;
            Of[idx] = (o[dt][qtl][rr] + Of[idx]) * rl;
          }
      }
    }
    __syncthreads();
    {
      int dcol = hh * DH + lane;
      float iw = __builtin_amdgcn_rcpf(1.f + fabsf(wout[dcol]));
      float bo = bout[dcol];
#pragma unroll
      for (int rr = 0; rr < 16; rr++) {
        int row = wave * 16 + rr;
        float th = Of[row * 68 + lane] * iw + bo;
        float sn, cs; fsincos(th, &sn, &cs);
        out[((size_t)b * SS + q0 + row) * DD + dcol] = cs + sn;
      }
    }
  }
}

extern "C" void kernel_launch(void* const* d_in, const int* in_sizes, int n_in,
                              void* d_out, int out_size, void* d_ws, size_t ws_size,
                              hipStream_t stream) {
  (void)in_sizes; (void)n_in; (void)out_size; (void)ws_size;
  const float* x   = (const float*)d_in[0];
  const float* wq  = (const float*)d_in[1];
  const float* bq  = (const float*)d_in[2];
  const float* phq = (const float*)d_in[3];
  const float* wk  = (const float*)d_in[4];
  const float* bk  = (const float*)d_in[5];
  const float* phk = (const float*)d_in[6];
  const float* wv  = (const float*)d_in[7];
  const float* bv  = (const float*)d_in[8];
  const float* wo  = (const float*)d_in[9];
  const float* bo  = (const float*)d_in[10];

  _Float16* Qd  = (_Float16*)d_ws;
  _Float16* Kd  = Qd + (size_t)BB * HH * SS * DQK;             // +16.78 MB
  _Float16* Vtd = Kd + (size_t)BB * HH * SS * DQK;             // +16.78 MB
  // control block after V (offset 41,943,040), then partial blobs (37.7 MB)
  char* ctl = (char*)(Vtd + (size_t)BB * HH * SS * DH);
  unsigned* ctr   = (unsigned*)ctl;          // 8 queue counters
  unsigned* flags = ctr + 8;                 // 512 split-pair flags
  float* blobs = (float*)(ctl + 4096);       // 1024 x 256 x 36 f32

  hipMemsetAsync(ctl, 0, (8 + 512) * 4, stream);
  gen_qkv<<<BB * HH * (SS / 64), 256, 0, stream>>>(
      x, wq, bq, phq, wk, bk, phk, wv, bv, Qd, Kd, Vtd);
  flash_attn<<<768, 256, 0, stream>>>(
      Qd, Kd, Vtd, wo, bo, (float*)d_out, ctr, flags, blobs);
}

// Round 6
// 147.850 us; speedup vs baseline: 2.8107x; 2.8107x over previous
//
#include <hip/hip_runtime.h>
#include <hip/hip_bf16.h>
#include <math.h>

#define BB 2
#define SS 2048
#define HH 16
#define DH 64
#define DQK 128
#define DD (HH*DH)
// Q folded scale = (1/sqrt(128)) * log2(e)  -> scores arrive in log2 domain
#define QS2   0.12751758f
// 8 * log2(e): fixed-max bias in log2 domain (cancels exactly in softmax)
#define EBIAS 11.5415605f

typedef _Float16 half8_t __attribute__((ext_vector_type(8)));
typedef _Float16 half4_t __attribute__((ext_vector_type(4)));
typedef __fp16  fp16x2_t __attribute__((ext_vector_type(2)));   // cvt_pkrtz result type
typedef float f32x4_t __attribute__((ext_vector_type(4)));
typedef float f32x4v __attribute__((ext_vector_type(4)));

__device__ __forceinline__ void fsincos(float th, float* sn, float* cs) {
  float rev = th * 0.15915494309189535f;
  rev -= floorf(rev);
  float ang = rev * 6.283185307179586f;
  *sn = __sinf(ang);
  *cs = __cosf(ang);
}

// async global->LDS DMA, 16B/lane, LDS dest = uniform base + lane*16
__device__ __forceinline__ void dma16(const void* g, void* l) {
  __builtin_amdgcn_global_load_lds(
      (const __attribute__((address_space(1))) unsigned int*)g,
      (__attribute__((address_space(3))) unsigned int*)l, 16, 0, 0);
}

// Block per (bh, s-tile of 64). Emits:
//   Q  row-major [bh][s][128], scale QS2 folded (log2-domain scores)
//   K  swizzled  [bh][ktile64][d8 0..15][key 0..63] 16B units
//   V  swizzled  [bh][ktile64][k8 0..7][dv 0..63]  16B units
__global__ __launch_bounds__(256) void gen_qkv(
    const float* __restrict__ x,
    const float* __restrict__ wq, const float* __restrict__ bq,
    const float* __restrict__ phq,
    const float* __restrict__ wk, const float* __restrict__ bk,
    const float* __restrict__ phk,
    const float* __restrict__ wv, const float* __restrict__ bv,
    _Float16* __restrict__ Qd, _Float16* __restrict__ Kd, _Float16* __restrict__ Vtd)
{
  int stile = blockIdx.x & 31;
  int bh    = blockIdx.x >> 5;
  int b = bh >> 4, h = bh & 15;
  int t = threadIdx.x;
  int sl = t >> 2;                 // 0..63 (key/row within tile)
  int dq = (t & 3) << 4;           // 0,16,32,48
  int s  = stile * 64 + sl;

  __shared__ _Float16 Vl[64 * 65]; // transpose buffer, odd pitch

  const float* xr = x + (((size_t)b * SS + s) * HH + h) * DH + dq;
  float xv[16];
#pragma unroll
  for (int i = 0; i < 4; i++)
    *(f32x4v*)(&xv[i * 4]) = *(const f32x4v*)(xr + i * 4);

  int hd0 = h * DH + dq;
  float iwqv[16], vbq[16], vpq[16];
  float iwkv[16], vbk[16], vpk[16];
  float iwvv[16], vbv[16];
#pragma unroll
  for (int i = 0; i < 4; i++) {
    f32x4v w4, b4, p4;
    w4 = *(const f32x4v*)(wq + hd0 + i * 4);
    b4 = *(const f32x4v*)(bq + hd0 + i * 4);
    p4 = *(const f32x4v*)(phq + hd0 + i * 4);
#pragma unroll
    for (int j = 0; j < 4; j++) {
      iwqv[i*4+j] = __builtin_amdgcn_rcpf(1.f + fabsf(w4[j]));
      vbq[i*4+j] = b4[j]; vpq[i*4+j] = p4[j];
    }
    w4 = *(const f32x4v*)(wk + hd0 + i * 4);
    b4 = *(const f32x4v*)(bk + hd0 + i * 4);
    p4 = *(const f32x4v*)(phk + hd0 + i * 4);
#pragma unroll
    for (int j = 0; j < 4; j++) {
      iwkv[i*4+j] = __builtin_amdgcn_rcpf(1.f + fabsf(w4[j]));
      vbk[i*4+j] = b4[j]; vpk[i*4+j] = p4[j];
    }
    w4 = *(const f32x4v*)(wv + hd0 + i * 4);
    b4 = *(const f32x4v*)(bv + hd0 + i * 4);
#pragma unroll
    for (int j = 0; j < 4; j++) {
      iwvv[i*4+j] = __builtin_amdgcn_rcpf(1.f + fabsf(w4[j]));
      vbv[i*4+j] = b4[j];
    }
  }

  float tv = (float)s;
  _Float16 qc[16], qs[16], kc[16], ks[16];
#pragma unroll
  for (int i = 0; i < 16; i++) {
    int d = dq + i;
    {
      float th = xv[i] * iwqv[i] + vbq[i] + tv * vpq[i];
      float sn, cs; fsincos(th, &sn, &cs);
      qc[i] = (_Float16)(cs * QS2);
      qs[i] = (_Float16)(sn * QS2);
    }
    {
      float th = xv[i] * iwkv[i] + vbk[i] + tv * vpk[i];
      float sn, cs; fsincos(th, &sn, &cs);
      kc[i] = (_Float16)cs;
      ks[i] = (_Float16)sn;
    }
    {
      float th = xv[i] * iwvv[i] + vbv[i];
      float sn, cs; fsincos(th, &sn, &cs);
      Vl[d * 65 + sl] = (_Float16)(cs + sn);
    }
  }
  // Q row-major
  size_t qbase = ((size_t)bh * SS + s) * DQK;
#pragma unroll
  for (int i = 0; i < 2; i++) {
    *(half8_t*)(Qd + qbase + dq + i * 8)      = *(half8_t*)(&qc[i * 8]);
    *(half8_t*)(Qd + qbase + DH + dq + i * 8) = *(half8_t*)(&qs[i * 8]);
  }
  // K swizzled: cos dims d -> d8 = d/8; sin dims -> d8 = 8 + d/8
  {
    size_t ktb = ((size_t)bh * 32 + stile) * 8192;  // f16 base of 16KB tile
    int fo0 = (t & 3) * 2;
    *(half8_t*)(Kd + ktb + ((size_t)(fo0    ) * 64 + sl) * 8) = *(half8_t*)(&kc[0]);
    *(half8_t*)(Kd + ktb + ((size_t)(fo0 + 1) * 64 + sl) * 8) = *(half8_t*)(&kc[8]);
    *(half8_t*)(Kd + ktb + ((size_t)(fo0 + 8) * 64 + sl) * 8) = *(half8_t*)(&ks[0]);
    *(half8_t*)(Kd + ktb + ((size_t)(fo0 + 9) * 64 + sl) * 8) = *(half8_t*)(&ks[8]);
  }
  __syncthreads();
  // V swizzled: unit (k8, dv) = V[dv][keys k8*8..+7]; 2 units/thread, coalesced
#pragma unroll
  for (int i = 0; i < 2; i++) {
    int u = t * 2 + i;
    int dv = u & 63, ku = u >> 6;    // ku 0..7
    _Float16 tmp[8];
#pragma unroll
    for (int jj = 0; jj < 8; jj++) tmp[jj] = Vl[dv * 65 + ku * 8 + jj];
    *(half8_t*)(Vtd + (((size_t)bh * 32 + stile) * 8 + ku) * 512 + dv * 8) =
        *(half8_t*)tmp;
  }
}

// R10 = R0 proven structure + depth-2 DMA ring (T3/T4).
// Diagnosis: R0/R3 both pinned at ~50us regardless of occupancy; per-chunk
// real work ~0.25us but advance rate 1.6us/chunk => per-chunk global->LDS
// latency exposed by __syncthreads' mandatory vmcnt(0) drain. Fix: 3-buffer
// ring, raw s_barrier + counted s_waitcnt vmcnt(6) (waits only for loads
// issued TWO chunks ago; never drains the newest prefetch). vmcnt(0) only
// on the final chunk. Q-frag loads issued first (oldest) so the first
// counted wait retires them too. 72KB LDS -> 2 blocks/CU; occupancy ceiling
// 25% -- acceptable: R3 proved occupancy is not the binding constraint.
__global__ __launch_bounds__(256) void flash_attn(
    const _Float16* __restrict__ Qd, const _Float16* __restrict__ Kd,
    const _Float16* __restrict__ Vtd,
    const float* __restrict__ wout, const float* __restrict__ bout,
    float* __restrict__ out)
{
  int qt = 31 - (blockIdx.x >> 5);   // LPT: heaviest first
  int bh = blockIdx.x & 31;          // XCD = bh % 8
  int b  = bh >> 4, hh = bh & 15;
  int nch = qt + 1;
  int q0 = qt * 64;
  int wave = threadIdx.x >> 6;
  int lane = threadIdx.x & 63;
  int lm = lane & 15, lq = lane >> 4;
  int qh = wave >> 1;
  int kh = wave & 1;

  __shared__ __align__(16) _Float16 KV[3][12288];   // ring: K 16KB + V 8KB each

  const _Float16* Kg = Kd + (size_t)bh * 32 * 8192;
  const _Float16* Vg = Vtd + (size_t)bh * 32 * 4096;

  // Q B-frags FIRST (oldest in vmcnt FIFO): B[n=q][k=c*32+lq*8+j]
  const _Float16* Qb = Qd + ((size_t)bh * SS + q0 + qh * 32) * DQK;
  half8_t aq[2][4];
#pragma unroll
  for (int qtl = 0; qtl < 2; qtl++)
#pragma unroll
    for (int c = 0; c < 4; c++)
      aq[qtl][c] = *(const half8_t*)(Qb + (qtl * 16 + lm) * DQK + c * 32 + lq * 8);
  asm volatile("" ::: "memory");   // pin Q-load issue before DMA issue

  // stage chunk c into ring buffer c%3 (6 vmcnt items per wave: 4 K + 2 V)
  auto STAGE = [&](int c) {
    int rb = c % 3;
    const _Float16* gK = Kg + (size_t)c * 8192;
    const _Float16* gV = Vg + (size_t)c * 4096;
#pragma unroll
    for (int i = 0; i < 4; i++)
      dma16(gK + (size_t)(wave * 4 + i) * 512 + lane * 8, &KV[rb][(wave * 4 + i) * 512]);
#pragma unroll
    for (int i = 0; i < 2; i++)
      dma16(gV + (size_t)(wave * 2 + i) * 512 + lane * 8, &KV[rb][8192 + (wave * 2 + i) * 512]);
  };

  STAGE(0);
  if (nch > 1) STAGE(1);

  f32x4_t o[4][2];   // [dv-tile][q-tile], elem = O^T[dt*16+lq*4+r][qtl*16+lm]
  float l[2] = {0.f, 0.f};
#pragma unroll
  for (int dt = 0; dt < 4; dt++)
#pragma unroll
    for (int qtl = 0; qtl < 2; qtl++) o[dt][qtl] = (f32x4_t){0.f, 0.f, 0.f, 0.f};

  const f32x4_t cinit = (f32x4_t){-EBIAS, -EBIAS, -EBIAS, -EBIAS};

  for (int kt = 0; kt < nch; ++kt) {
    // counted wait: chunk kt's 6 DMAs are the oldest outstanding; leave the
    // newer prefetch (chunk kt+1) in flight. Only the last chunk drains.
    if (kt + 1 < nch) asm volatile("s_waitcnt vmcnt(6)" ::: "memory");
    else              asm volatile("s_waitcnt vmcnt(0)" ::: "memory");
    __builtin_amdgcn_s_barrier();    // all waves' slices of chunk kt landed;
    asm volatile("" ::: "memory");   // all waves done computing chunk kt-1
    if (kt + 2 < nch) STAGE(kt + 2); // overwrites buf[(kt-1)%3]: safe (barrier)

    int rb = kt % 3;
    const _Float16* lK = &KV[rb][0];
    const _Float16* lV = &KV[rb][8192];
    int k0 = kt * 64;

    // S^T - EBIAS = K Q^T + (-EBIAS) : C-layout (key = lq*4+r, q = lm)
    f32x4_t cST[2][2];
    cST[0][0] = cST[0][1] = cST[1][0] = cST[1][1] = cinit;
#pragma unroll
    for (int c = 0; c < 4; c++) {
      half8_t k0f = *(const half8_t*)(lK + ((size_t)(c * 4 + lq) * 64 + kh * 32 + lm) * 8);
      half8_t k1f = *(const half8_t*)(lK + ((size_t)(c * 4 + lq) * 64 + kh * 32 + 16 + lm) * 8);
      cST[0][0] = __builtin_amdgcn_mfma_f32_16x16x32_f16(k0f, aq[0][c], cST[0][0], 0, 0, 0);
      cST[0][1] = __builtin_amdgcn_mfma_f32_16x16x32_f16(k0f, aq[1][c], cST[0][1], 0, 0, 0);
      cST[1][0] = __builtin_amdgcn_mfma_f32_16x16x32_f16(k1f, aq[0][c], cST[1][0], 0, 0, 0);
      cST[1][1] = __builtin_amdgcn_mfma_f32_16x16x32_f16(k1f, aq[1][c], cST[1][1], 0, 0, 0);
    }

    // p = 2^(s2) in-register; pack -> B-frags (B[n=q=lm][k=lq*4+i])
    bool maskit = (kt == nch - 1);
    half4_t pb[2][2];
#pragma unroll
    for (int ktl = 0; ktl < 2; ktl++)
#pragma unroll
      for (int qtl = 0; qtl < 2; qtl++) {
        float pf[4];
#pragma unroll
        for (int r = 0; r < 4; r++) {
          float sv = cST[ktl][qtl][r];
          if (maskit) {
            int key  = k0 + kh * 32 + ktl * 16 + lq * 4 + r;
            int qrow = q0 + qh * 32 + qtl * 16 + lm;
            if (key > qrow) sv = -1e30f;
          }
          pf[r] = __builtin_exp2f(sv);
          l[qtl] += pf[r];
        }
        fp16x2_t h01 = __builtin_amdgcn_cvt_pkrtz(pf[0], pf[1]);
        fp16x2_t h23 = __builtin_amdgcn_cvt_pkrtz(pf[2], pf[3]);
        pb[ktl][qtl] = (half4_t){(_Float16)h01.x, (_Float16)h01.y,
                                 (_Float16)h23.x, (_Float16)h23.y};
      }

    // O^T += V^T P^T : A = V^T frag (m=dv, k=key lq*4+i), 16 MFMA 16x16x16
#pragma unroll
    for (int dt = 0; dt < 4; dt++)
#pragma unroll
      for (int kg = 0; kg < 2; kg++) {
        half4_t vf = *(const half4_t*)(lV +
            ((size_t)(kh * 4 + kg * 2 + (lq >> 1)) * 64 + dt * 16 + lm) * 8 + (lq & 1) * 4);
        o[dt][0] = __builtin_amdgcn_mfma_f32_16x16x16f16(vf, pb[kg][0], o[dt][0], 0, 0, 0);
        o[dt][1] = __builtin_amdgcn_mfma_f32_16x16x16f16(vf, pb[kg][1], o[dt][1], 0, 0, 0);
      }
  }

  // reduce l over lq groups (keys): all lanes end with l for q = qtl*16+lm
#pragma unroll
  for (int qtl = 0; qtl < 2; qtl++) {
    l[qtl] += __shfl_xor(l[qtl], 16);
    l[qtl] += __shfl_xor(l[qtl], 32);
  }

  // combine kh halves + normalize via LDS overlay (no DMA outstanding: last
  // chunk waited vmcnt(0)). Row-major Of[row][pitch 68], 17664 B < 72 KB.
  float* Of = (float*)&KV[0][0];
  float* Lf = Of + 64 * 68;
  __syncthreads();
  if (kh == 1) {
#pragma unroll
    for (int qtl = 0; qtl < 2; qtl++) {
      int row = qh * 32 + qtl * 16 + lm;
#pragma unroll
      for (int dt = 0; dt < 4; dt++)
#pragma unroll
        for (int rr = 0; rr < 4; rr++)
          Of[row * 68 + dt * 16 + lq * 4 + rr] = o[dt][qtl][rr];
      if (lq == 0) Lf[row] = l[qtl];
    }
  }
  __syncthreads();
  if (kh == 0) {
#pragma unroll
    for (int qtl = 0; qtl < 2; qtl++) {
      int row = qh * 32 + qtl * 16 + lm;
      float rl = __builtin_amdgcn_rcpf(l[qtl] + Lf[row]);
#pragma unroll
      for (int dt = 0; dt < 4; dt++)
#pragma unroll
        for (int rr = 0; rr < 4; rr++) {
          int idx = row * 68 + dt * 16 + lq * 4 + rr;
          Of[idx] = (o[dt][qtl][rr] + Of[idx]) * rl;
        }
    }
  }
  __syncthreads();
  {
    int dcol = hh * DH + lane;
    float iw = __builtin_amdgcn_rcpf(1.f + fabsf(wout[dcol]));
    float bo = bout[dcol];
#pragma unroll
    for (int rr = 0; rr < 16; rr++) {
      int row = wave * 16 + rr;
      float th = Of[row * 68 + lane] * iw + bo;
      float sn, cs; fsincos(th, &sn, &cs);
      out[((size_t)b * SS + q0 + row) * DD + dcol] = cs + sn;
    }
  }
}

extern "C" void kernel_launch(void* const* d_in, const int* in_sizes, int n_in,
                              void* d_out, int out_size, void* d_ws, size_t ws_size,
                              hipStream_t stream) {
  (void)in_sizes; (void)n_in; (void)out_size; (void)ws_size;
  const float* x   = (const float*)d_in[0];
  const float* wq  = (const float*)d_in[1];
  const float* bq  = (const float*)d_in[2];
  const float* phq = (const float*)d_in[3];
  const float* wk  = (const float*)d_in[4];
  const float* bk  = (const float*)d_in[5];
  const float* phk = (const float*)d_in[6];
  const float* wv  = (const float*)d_in[7];
  const float* bv  = (const float*)d_in[8];
  const float* wo  = (const float*)d_in[9];
  const float* bo  = (const float*)d_in[10];

  _Float16* Qd  = (_Float16*)d_ws;
  _Float16* Kd  = Qd + (size_t)BB * HH * SS * DQK;
  _Float16* Vtd = Kd + (size_t)BB * HH * SS * DQK;

  gen_qkv<<<BB * HH * (SS / 64), 256, 0, stream>>>(
      x, wq, bq, phq, wk, bk, phk, wv, bv, Qd, Kd, Vtd);
  flash_attn<<<32 * 32, 256, 0, stream>>>(
      Qd, Kd, Vtd, wo, bo, (float*)d_out);
}

// Round 7
// 140.561 us; speedup vs baseline: 2.9564x; 1.0519x over previous
//
#include <hip/hip_runtime.h>
#include <hip/hip_bf16.h>
#include <math.h>

#define BB 2
#define SS 2048
#define HH 16
#define DH 64
#define DQK 128
#define DD (HH*DH)
// Q folded scale = (1/sqrt(128)) * log2(e)  -> scores arrive in log2 domain
#define QS2   0.12751758f
// 8 * log2(e): fixed-max bias in log2 domain (cancels exactly in softmax)
#define EBIAS 11.5415605f

typedef _Float16 half8_t __attribute__((ext_vector_type(8)));
typedef _Float16 half4_t __attribute__((ext_vector_type(4)));
typedef float f32x4_t __attribute__((ext_vector_type(4)));
typedef float f32x4v __attribute__((ext_vector_type(4)));

// R7: direct hardware trig on REVOLUTIONS (v_sin_f32: D=sin(S0*2pi)).
// Old path did fract(th/2pi) then *2pi then __sinf (which re-multiplies by
// 1/2pi) -- double range-reduction, 2 extra muls per pair. gen_qkv is
// TRANS-bound (R3's VALU-only edits moved nothing), so cut TRANS+prep ops.
__device__ __forceinline__ void fsincos(float th, float* sn, float* cs) {
  float rev = th * 0.15915494309189535f;
  rev -= floorf(rev);
  *sn = __builtin_amdgcn_sinf(rev);
  *cs = __builtin_amdgcn_cosf(rev);
}
// cos(th)+sin(th) = sqrt(2)*sin(th + pi/4): ONE transcendental, not two.
__device__ __forceinline__ float fsc_sum(float th) {
  float rev = th * 0.15915494309189535f + 0.125f;
  rev -= floorf(rev);
  return 1.41421356237f * __builtin_amdgcn_sinf(rev);
}

// async global->LDS DMA, 16B/lane, LDS dest = uniform base + lane*16
__device__ __forceinline__ void dma16(const void* g, void* l) {
  __builtin_amdgcn_global_load_lds(
      (const __attribute__((address_space(1))) unsigned int*)g,
      (__attribute__((address_space(3))) unsigned int*)l, 16, 0, 0);
}

// Block per (bh, s-tile of 64). Emits:
//   Q  row-major [bh][s][128], scale QS2 folded (log2-domain scores)
//   K  swizzled  [bh][ktile64][d8 0..15][key 0..63] 16B units
//   V  swizzled  [bh][ktile64][k8 0..7][dv 0..63]  16B units
__global__ __launch_bounds__(256) void gen_qkv(
    const float* __restrict__ x,
    const float* __restrict__ wq, const float* __restrict__ bq,
    const float* __restrict__ phq,
    const float* __restrict__ wk, const float* __restrict__ bk,
    const float* __restrict__ phk,
    const float* __restrict__ wv, const float* __restrict__ bv,
    _Float16* __restrict__ Qd, _Float16* __restrict__ Kd, _Float16* __restrict__ Vtd)
{
  int stile = blockIdx.x & 31;
  int bh    = blockIdx.x >> 5;
  int b = bh >> 4, h = bh & 15;
  int t = threadIdx.x;
  int sl = t >> 2;                 // 0..63 (key/row within tile)
  int dq = (t & 3) << 4;           // 0,16,32,48
  int s  = stile * 64 + sl;

  __shared__ _Float16 Vl[64 * 65]; // transpose buffer, odd pitch

  const float* xr = x + (((size_t)b * SS + s) * HH + h) * DH + dq;
  float xv[16];
#pragma unroll
  for (int i = 0; i < 4; i++)
    *(f32x4v*)(&xv[i * 4]) = *(const f32x4v*)(xr + i * 4);

  int hd0 = h * DH + dq;
  float iwqv[16], vbq[16], vpq[16];
  float iwkv[16], vbk[16], vpk[16];
  float iwvv[16], vbv[16];
#pragma unroll
  for (int i = 0; i < 4; i++) {
    f32x4v w4, b4, p4;
    w4 = *(const f32x4v*)(wq + hd0 + i * 4);
    b4 = *(const f32x4v*)(bq + hd0 + i * 4);
    p4 = *(const f32x4v*)(phq + hd0 + i * 4);
#pragma unroll
    for (int j = 0; j < 4; j++) {
      iwqv[i*4+j] = __builtin_amdgcn_rcpf(1.f + fabsf(w4[j]));
      vbq[i*4+j] = b4[j]; vpq[i*4+j] = p4[j];
    }
    w4 = *(const f32x4v*)(wk + hd0 + i * 4);
    b4 = *(const f32x4v*)(bk + hd0 + i * 4);
    p4 = *(const f32x4v*)(phk + hd0 + i * 4);
#pragma unroll
    for (int j = 0; j < 4; j++) {
      iwkv[i*4+j] = __builtin_amdgcn_rcpf(1.f + fabsf(w4[j]));
      vbk[i*4+j] = b4[j]; vpk[i*4+j] = p4[j];
    }
    w4 = *(const f32x4v*)(wv + hd0 + i * 4);
    b4 = *(const f32x4v*)(bv + hd0 + i * 4);
#pragma unroll
    for (int j = 0; j < 4; j++) {
      iwvv[i*4+j] = __builtin_amdgcn_rcpf(1.f + fabsf(w4[j]));
      vbv[i*4+j] = b4[j];
    }
  }

  float tv = (float)s;
  _Float16 qc[16], qs[16], kc[16], ks[16];
#pragma unroll
  for (int i = 0; i < 16; i++) {
    int d = dq + i;
    {
      float th = xv[i] * iwqv[i] + vbq[i] + tv * vpq[i];
      float sn, cs; fsincos(th, &sn, &cs);
      qc[i] = (_Float16)(cs * QS2);
      qs[i] = (_Float16)(sn * QS2);
    }
    {
      float th = xv[i] * iwkv[i] + vbk[i] + tv * vpk[i];
      float sn, cs; fsincos(th, &sn, &cs);
      kc[i] = (_Float16)cs;
      ks[i] = (_Float16)sn;
    }
    {
      float th = xv[i] * iwvv[i] + vbv[i];
      Vl[d * 65 + sl] = (_Float16)fsc_sum(th);
    }
  }
  // Q row-major
  size_t qbase = ((size_t)bh * SS + s) * DQK;
#pragma unroll
  for (int i = 0; i < 2; i++) {
    *(half8_t*)(Qd + qbase + dq + i * 8)      = *(half8_t*)(&qc[i * 8]);
    *(half8_t*)(Qd + qbase + DH + dq + i * 8) = *(half8_t*)(&qs[i * 8]);
  }
  // K swizzled: cos dims d -> d8 = d/8; sin dims -> d8 = 8 + d/8
  {
    size_t ktb = ((size_t)bh * 32 + stile) * 8192;  // f16 base of 16KB tile
    int fo0 = (t & 3) * 2;
    *(half8_t*)(Kd + ktb + ((size_t)(fo0    ) * 64 + sl) * 8) = *(half8_t*)(&kc[0]);
    *(half8_t*)(Kd + ktb + ((size_t)(fo0 + 1) * 64 + sl) * 8) = *(half8_t*)(&kc[8]);
    *(half8_t*)(Kd + ktb + ((size_t)(fo0 + 8) * 64 + sl) * 8) = *(half8_t*)(&ks[0]);
    *(half8_t*)(Kd + ktb + ((size_t)(fo0 + 9) * 64 + sl) * 8) = *(half8_t*)(&ks[8]);
  }
  __syncthreads();
  // V swizzled: unit (k8, dv) = V[dv][keys k8*8..+7]; 2 units/thread, coalesced
#pragma unroll
  for (int i = 0; i < 2; i++) {
    int u = t * 2 + i;
    int dv = u & 63, ku = u >> 6;    // ku 0..7
    _Float16 tmp[8];
#pragma unroll
    for (int jj = 0; jj < 8; jj++) tmp[jj] = Vl[dv * 65 + ku * 8 + jj];
    *(half8_t*)(Vtd + (((size_t)bh * 32 + stile) * 8 + ku) * 512 + dv * 8) =
        *(half8_t*)tmp;
  }
}

// R7 flash = byte-for-byte the proven R0 structure (50.8us: 2-buffer LDS
// double-buffer, __syncthreads drain, LDS V, pitch-68 epilogue overlay,
// 3 blocks/CU) + s_setprio around MFMA clusters (T5) + 1-TRANS epilogue.
// R6's counted-vmcnt ring REGRESSED (57.7us, bank conflicts 24x from DMA
// writes overlapping ds_reads; occupancy 17%): do not re-attempt without
// a conflict-free write layout.
__global__ __launch_bounds__(256) void flash_attn(
    const _Float16* __restrict__ Qd, const _Float16* __restrict__ Kd,
    const _Float16* __restrict__ Vtd,
    const float* __restrict__ wout, const float* __restrict__ bout,
    float* __restrict__ out)
{
  int qt = 31 - (blockIdx.x >> 5);   // LPT: heaviest first
  int bh = blockIdx.x & 31;          // XCD = bh % 8
  int b  = bh >> 4, hh = bh & 15;
  int nch = qt + 1;
  int q0 = qt * 64;
  int wave = threadIdx.x >> 6;
  int lane = threadIdx.x & 63;
  int lm = lane & 15, lq = lane >> 4;
  int qh = wave >> 1;
  int kh = wave & 1;

  __shared__ __align__(16) _Float16 KV[2][12288];   // per buf: K 16KB + V 8KB

  const _Float16* Kg = Kd + (size_t)bh * 32 * 8192;
  const _Float16* Vg = Vtd + (size_t)bh * 32 * 4096;

  {  // preload chunk 0 -> buf 0 (flies while Q frags load below)
#pragma unroll
    for (int i = 0; i < 4; i++)
      dma16(Kg + (size_t)(wave * 4 + i) * 512 + lane * 8, &KV[0][(wave * 4 + i) * 512]);
#pragma unroll
    for (int i = 0; i < 2; i++)
      dma16(Vg + (size_t)(wave * 2 + i) * 512 + lane * 8, &KV[0][8192 + (wave * 2 + i) * 512]);
  }

  // Q B-frags resident: B[n=q][k=c*32+lq*8+j]
  const _Float16* Qb = Qd + ((size_t)bh * SS + q0 + qh * 32) * DQK;
  half8_t aq[2][4];
#pragma unroll
  for (int qtl = 0; qtl < 2; qtl++)
#pragma unroll
    for (int c = 0; c < 4; c++)
      aq[qtl][c] = *(const half8_t*)(Qb + (qtl * 16 + lm) * DQK + c * 32 + lq * 8);

  f32x4_t o[4][2];   // [dv-tile][q-tile], element = O^T[dt*16+lq*4+r][qtl*16+lm]
  float l[2] = {0.f, 0.f};
#pragma unroll
  for (int dt = 0; dt < 4; dt++)
#pragma unroll
    for (int qtl = 0; qtl < 2; qtl++) o[dt][qtl] = (f32x4_t){0.f, 0.f, 0.f, 0.f};

  const f32x4_t cinit = (f32x4_t){-EBIAS, -EBIAS, -EBIAS, -EBIAS};

  for (int kt = 0; kt < nch; ++kt) {
    int bf = kt & 1;
    __syncthreads();   // drains DMA (vmcnt0 before barrier) + compute of kt-1
    if (kt + 1 < nch) {
      int nb = (kt + 1) & 1;
      const _Float16* gK = Kg + (size_t)(kt + 1) * 8192;
      const _Float16* gV = Vg + (size_t)(kt + 1) * 4096;
#pragma unroll
      for (int i = 0; i < 4; i++)
        dma16(gK + (size_t)(wave * 4 + i) * 512 + lane * 8, &KV[nb][(wave * 4 + i) * 512]);
#pragma unroll
      for (int i = 0; i < 2; i++)
        dma16(gV + (size_t)(wave * 2 + i) * 512 + lane * 8, &KV[nb][8192 + (wave * 2 + i) * 512]);
    }

    const _Float16* lK = &KV[bf][0];
    const _Float16* lV = &KV[bf][8192];
    int k0 = kt * 64;

    // S^T - EBIAS = K Q^T + (-EBIAS) : C-layout (key = lq*4+r, q = lm)
    f32x4_t cST[2][2];
    cST[0][0] = cST[0][1] = cST[1][0] = cST[1][1] = cinit;
    __builtin_amdgcn_s_setprio(1);
#pragma unroll
    for (int c = 0; c < 4; c++) {
      half8_t k0f = *(const half8_t*)(lK + ((size_t)(c * 4 + lq) * 64 + kh * 32 + lm) * 8);
      half8_t k1f = *(const half8_t*)(lK + ((size_t)(c * 4 + lq) * 64 + kh * 32 + 16 + lm) * 8);
      cST[0][0] = __builtin_amdgcn_mfma_f32_16x16x32_f16(k0f, aq[0][c], cST[0][0], 0, 0, 0);
      cST[0][1] = __builtin_amdgcn_mfma_f32_16x16x32_f16(k0f, aq[1][c], cST[0][1], 0, 0, 0);
      cST[1][0] = __builtin_amdgcn_mfma_f32_16x16x32_f16(k1f, aq[0][c], cST[1][0], 0, 0, 0);
      cST[1][1] = __builtin_amdgcn_mfma_f32_16x16x32_f16(k1f, aq[1][c], cST[1][1], 0, 0, 0);
    }
    __builtin_amdgcn_s_setprio(0);

    // p = 2^(s2) in-register; pack -> B-frags (B[n=q=lm][k=lq*4+i])
    bool maskit = (kt == nch - 1);
    half4_t pb[2][2];
#pragma unroll
    for (int ktl = 0; ktl < 2; ktl++)
#pragma unroll
      for (int qtl = 0; qtl < 2; qtl++) {
        float pf[4];
#pragma unroll
        for (int r = 0; r < 4; r++) {
          float sv = cST[ktl][qtl][r];
          if (maskit) {
            int key  = k0 + kh * 32 + ktl * 16 + lq * 4 + r;
            int qrow = q0 + qh * 32 + qtl * 16 + lm;
            if (key > qrow) sv = -1e30f;
          }
          pf[r] = __builtin_exp2f(sv);
          l[qtl] += pf[r];
        }
        pb[ktl][qtl] = (half4_t){(_Float16)pf[0], (_Float16)pf[1],
                                 (_Float16)pf[2], (_Float16)pf[3]};
      }

    // O^T += V^T P^T : A = V^T frag (m=dv, k=key lq*4+i), 16 MFMA 16x16x16
    __builtin_amdgcn_s_setprio(1);
#pragma unroll
    for (int dt = 0; dt < 4; dt++)
#pragma unroll
      for (int kg = 0; kg < 2; kg++) {
        half4_t vf = *(const half4_t*)(lV +
            ((size_t)(kh * 4 + kg * 2 + (lq >> 1)) * 64 + dt * 16 + lm) * 8 + (lq & 1) * 4);
        o[dt][0] = __builtin_amdgcn_mfma_f32_16x16x16f16(vf, pb[kg][0], o[dt][0], 0, 0, 0);
        o[dt][1] = __builtin_amdgcn_mfma_f32_16x16x16f16(vf, pb[kg][1], o[dt][1], 0, 0, 0);
      }
    __builtin_amdgcn_s_setprio(0);
  }

  // reduce l over lq groups (keys): all lanes end with l for q = qtl*16+lm
#pragma unroll
  for (int qtl = 0; qtl < 2; qtl++) {
    l[qtl] += __shfl_xor(l[qtl], 16);
    l[qtl] += __shfl_xor(l[qtl], 32);
  }

  // combine kh halves + normalize via LDS overlaid on the idle KV buffer
  // (last chunk used buf (nch-1)&1, so buf nch&1 is free), then epilogue.
  int sc = nch & 1;
  float* Of = (float*)&KV[sc][0];        // [row][pitch 68], 17664 B < 24576 B
  float* Lf = Of + 64 * 68;
  __syncthreads();
  if (kh == 1) {
#pragma unroll
    for (int qtl = 0; qtl < 2; qtl++) {
      int row = qh * 32 + qtl * 16 + lm;
#pragma unroll
      for (int dt = 0; dt < 4; dt++)
#pragma unroll
        for (int r = 0; r < 4; r++)
          Of[row * 68 + dt * 16 + lq * 4 + r] = o[dt][qtl][r];
      if (lq == 0) Lf[row] = l[qtl];
    }
  }
  __syncthreads();
  if (kh == 0) {
#pragma unroll
    for (int qtl = 0; qtl < 2; qtl++) {
      int row = qh * 32 + qtl * 16 + lm;
      float rl = 1.f / (l[qtl] + Lf[row]);
#pragma unroll
      for (int dt = 0; dt < 4; dt++)
#pragma unroll
        for (int r = 0; r < 4; r++) {
          int idx = row * 68 + dt * 16 + lq * 4 + r;
          Of[idx] = (o[dt][qtl][r] + Of[idx]) * rl;
        }
    }
  }
  __syncthreads();
  {
    int dcol = hh * DH + lane;
    float iw = 1.f / (1.f + fabsf(wout[dcol]));
    float bo = bout[dcol];
#pragma unroll
    for (int rr = 0; rr < 16; rr++) {
      int row = wave * 16 + rr;
      float th = Of[row * 68 + lane] * iw + bo;
      out[((size_t)b * SS + q0 + row) * DD + dcol] = fsc_sum(th);
    }
  }
}

extern "C" void kernel_launch(void* const* d_in, const int* in_sizes, int n_in,
                              void* d_out, int out_size, void* d_ws, size_t ws_size,
                              hipStream_t stream) {
  (void)in_sizes; (void)n_in; (void)out_size; (void)ws_size;
  const float* x   = (const float*)d_in[0];
  const float* wq  = (const float*)d_in[1];
  const float* bq  = (const float*)d_in[2];
  const float* phq = (const float*)d_in[3];
  const float* wk  = (const float*)d_in[4];
  const float* bk  = (const float*)d_in[5];
  const float* phk = (const float*)d_in[6];
  const float* wv  = (const float*)d_in[7];
  const float* bv  = (const float*)d_in[8];
  const float* wo  = (const float*)d_in[9];
  const float* bo  = (const float*)d_in[10];

  _Float16* Qd  = (_Float16*)d_ws;
  _Float16* Kd  = Qd + (size_t)BB * HH * SS * DQK;
  _Float16* Vtd = Kd + (size_t)BB * HH * SS * DQK;

  gen_qkv<<<BB * HH * (SS / 64), 256, 0, stream>>>(
      x, wq, bq, phq, wk, bk, phk, wv, bv, Qd, Kd, Vtd);
  flash_attn<<<32 * 32, 256, 0, stream>>>(
      Qd, Kd, Vtd, wo, bo, (float*)d_out);
}